// Round 1
// baseline (313.718 us; speedup 1.0000x reference)
//
#include <hip/hip_runtime.h>

typedef __bf16 bf16x8 __attribute__((ext_vector_type(8)));
typedef __bf16 bf16x4 __attribute__((ext_vector_type(4)));
typedef float  f32x4  __attribute__((ext_vector_type(4)));

// Shapes: B=64, C=256, T=128, V=25, K=3, G=4, Cg=64, dk=16
// ws layout: xm (64*256*25 f32 = 1,638,400 B) | afull (64*3*32*32 bf16 = 393,216 B)

// ---------------- Kernel 1: temporal mean xm[b,c,v] ----------------
__global__ __launch_bounds__(256)
void k_tmean(const float* __restrict__ x, float* __restrict__ xm)
{
    const int bid = blockIdx.x;            // b*256 + c
    const int tid = threadIdx.x;
    const int r = tid >> 5, vv = tid & 31;
    const float* base = x + (size_t)bid * 3200;
    float acc = 0.f;
    if (vv < 25) {
#pragma unroll
        for (int i = 0; i < 16; ++i)
            acc += base[(r + i * 8) * 25 + vv];
    }
    __shared__ float red[8][32];
    red[r][vv] = acc;
    __syncthreads();
    if (tid < 25) {
        float s = 0.f;
#pragma unroll
        for (int rr = 0; rr < 8; ++rr) s += red[rr][tid];
        xm[(size_t)bid * 25 + tid] = s * (1.0f / 128.0f);
    }
}

// ---------------- Kernel 2: A_dyn + Afull tables (one block per b) ----------------
__global__ __launch_bounds__(256)
void k_adyn(const float* __restrict__ xm, const float* __restrict__ A,
            const float* __restrict__ Wq, const float* __restrict__ Wk,
            const float* __restrict__ alpha, __bf16* __restrict__ afull)
{
    const int b = blockIdx.x, tid = threadIdx.x;
    __shared__ float xm_s[256 * 25];
    __shared__ float q_s[64 * 25];
    __shared__ float k_s[64 * 25];
    __shared__ float sm_s[4][25][25];
    __shared__ float ad_s[25][25];
    __shared__ float rs_s[3][25];

    for (int i = tid; i < 256 * 25; i += 256) xm_s[i] = xm[(size_t)b * 6400 + i];
    for (int i = tid; i < 75; i += 256) {
        int k3 = i / 25, v = i - (i / 25) * 25;
        float s = 0.f;
        for (int w = 0; w < 25; ++w) s += A[(k3 * 25 + v) * 25 + w];
        rs_s[k3][v] = fmaxf(s, 1e-6f);
    }
    __syncthreads();

    // q = Wq@xm, k = Wk@xm (T-mean already applied in xm)
    for (int i = tid; i < 1600; i += 256) {
        int o = i / 25, v = i - o * 25;
        const float* wq = Wq + o * 256;
        const float* wk = Wk + o * 256;
        float aq = 0.f, ak = 0.f;
        for (int c = 0; c < 256; ++c) {
            float xv = xm_s[c * 25 + v];
            aq += wq[c] * xv;
            ak += wk[c] * xv;
        }
        q_s[i] = aq; k_s[i] = ak;
    }
    __syncthreads();

    // per-(g,v) logits over w, softmax (dk=16, /sqrt(dk)=0.25)
    if (tid < 100) {
        int g = tid / 25, v = tid - (tid / 25) * 25;
        float l[25];
#pragma unroll
        for (int w = 0; w < 25; ++w) {
            float s = 0.f;
#pragma unroll
            for (int d = 0; d < 16; ++d)
                s += q_s[(g * 16 + d) * 25 + v] * k_s[(g * 16 + d) * 25 + w];
            l[w] = s * 0.25f;
        }
        float mx = l[0];
#pragma unroll
        for (int w = 1; w < 25; ++w) mx = fmaxf(mx, l[w]);
        float den = 0.f;
#pragma unroll
        for (int w = 0; w < 25; ++w) { l[w] = expf(l[w] - mx); den += l[w]; }
        float rden = 1.f / den;
#pragma unroll
        for (int w = 0; w < 25; ++w) sm_s[g][v][w] = l[w] * rden;
    }
    __syncthreads();
    for (int i = tid; i < 625; i += 256) {
        int v = i / 25, w = i - (i / 25) * 25;
        ad_s[v][w] = 0.25f * (sm_s[0][v][w] + sm_s[1][v][w] + sm_s[2][v][w] + sm_s[3][v][w]);
    }
    __syncthreads();

    // Afull[b][k][v][w] = A_norm + tanh(alpha)*A_dyn, bf16, zero-padded 32x32
    const float al = tanhf(alpha[0]);
    for (int i = tid; i < 3 * 32 * 32; i += 256) {
        int k3 = i >> 10, rem = i & 1023, v = rem >> 5, w = rem & 31;
        float val = 0.f;
        if (v < 25 && w < 25)
            val = A[(k3 * 25 + v) * 25 + w] / rs_s[k3][v] + al * ad_s[v][w];
        afull[(size_t)b * 3072 + i] = (__bf16)val;
    }
}

// ---------------- Kernel 3: fused agg (MFMA) + grouped conv (MFMA) + BN + residual ----------------
// block = (b, g, tt); 4 waves. LDS xagg[cc=t*25+v][c], c XOR-swizzled by ((cc&7)<<3).
__global__ __launch_bounds__(256)
void k_main(const float* __restrict__ x, const float* __restrict__ Wconv,
            const __bf16* __restrict__ afull,
            const float* __restrict__ gamma, const float* __restrict__ beta,
            const float* __restrict__ rmean, const float* __restrict__ rvar,
            float* __restrict__ out)
{
    const int bid = blockIdx.x;
    const int tt = bid & 7;
    const int g = (bid >> 3) & 3;
    const int b = bid >> 5;
    const int tid = threadIdx.x;
    const int wave = tid >> 6;
    const int lane = tid & 63;
    const int l15 = lane & 15;
    const int lg = lane >> 4;      // lane group 0..3 -> K-offset lg*8
    const int w0 = lg << 3;

    __shared__ __bf16 xagg[400 * 64];   // 51.2 KB

    // Load x A-fragments: agg rows = t_local*64 + c; wave owns M-tiles wave*16..+15.
    // Lane reads x[c, t, w0..w0+7] (w0=24 group: only w=24 valid, rest zero; B rows >=25 are zero anyway).
    bf16x8 xfrag[16];
#pragma unroll
    for (int m = 0; m < 16; ++m) {
        const int Mg = wave * 16 + m;
        const int t = Mg >> 2;
        const int c = ((Mg & 3) << 4) + l15;
        const float* p = x + (size_t)((b * 256 + g * 64 + c) * 128 + tt * 16 + t) * 25 + w0;
        bf16x8 f;
        if (lg < 3) {
#pragma unroll
            for (int j = 0; j < 8; ++j) f[j] = (__bf16)p[j];
        } else {
            f[0] = (__bf16)p[0];
#pragma unroll
            for (int j = 1; j < 8; ++j) f[j] = (__bf16)0.f;
        }
        xfrag[m] = f;
    }

    // BN constants: this lane's output channel (conv N-tile = wave)
    const int o_lane = (wave << 4) + l15;
    const int ch = (g << 6) + o_lane;
    const float inv = gamma[ch] / sqrtf(rvar[ch] + 1e-5f);
    const float bias = beta[ch] - rmean[ch] * inv;

    f32x4 acc[25];
#pragma unroll
    for (int i = 0; i < 25; ++i) acc[i] = (f32x4){0.f, 0.f, 0.f, 0.f};
    const f32x4 zero4 = {0.f, 0.f, 0.f, 0.f};

#pragma unroll 1
    for (int k3 = 0; k3 < 3; ++k3) {
        // agg B-frags: B[w, v] = A_k[v, w] -> rows of Afull[v][w0..w0+7]
        bf16x8 bA[2];
#pragma unroll
        for (int n = 0; n < 2; ++n) {
            const int v = (n << 4) + l15;
            bA[n] = *(const bf16x8*)(afull + (size_t)(b * 3 + k3) * 1024 + v * 32 + w0);
        }
        // conv B-frags: B[c, o] = W[o, c] -> Wconv[k][g][o][c0..c0+7]
        bf16x8 wf[2];
#pragma unroll
        for (int ks = 0; ks < 2; ++ks) {
            const float* wp = Wconv + (size_t)((k3 * 4 + g) * 64 + o_lane) * 64 + (ks << 5) + w0;
            bf16x8 f;
#pragma unroll
            for (int j = 0; j < 8; ++j) f[j] = (__bf16)wp[j];
            wf[ks] = f;
        }

        if (k3 > 0) __syncthreads();   // previous conv reads done before overwrite

        // aggregation: D[(t,c), v] = sum_w x[c,t,w] * A_k[v,w]  -> LDS (bf16, swizzled)
#pragma unroll
        for (int m = 0; m < 16; ++m) {
            const int Mg = wave * 16 + m;
            const int t = Mg >> 2;
            const int cbase = ((Mg & 3) << 4) + (lg << 2);
#pragma unroll
            for (int n = 0; n < 2; ++n) {
                f32x4 d = __builtin_amdgcn_mfma_f32_16x16x32_bf16(xfrag[m], bA[n], zero4, 0, 0, 0);
                const int v = (n << 4) + l15;
                if (v < 25) {
                    const int cc = t * 25 + v;
                    const int cidx = cbase ^ ((cc & 7) << 3);
                    bf16x4 h;
                    h[0] = (__bf16)d[0]; h[1] = (__bf16)d[1];
                    h[2] = (__bf16)d[2]; h[3] = (__bf16)d[3];
                    *(bf16x4*)(&xagg[cc * 64 + cidx]) = h;
                }
            }
        }
        __syncthreads();

        // conv (transposed): D[cc, o] += sum_c xagg[c, cc] * W[o, c]
#pragma unroll
        for (int mcc = 0; mcc < 25; ++mcc) {
            const int cc = (mcc << 4) + l15;
            const int sw = (cc & 7) << 3;
#pragma unroll
            for (int ks = 0; ks < 2; ++ks) {
                const int cidx = ((ks << 5) + w0) ^ sw;
                bf16x8 aF = *(const bf16x8*)(&xagg[cc * 64 + cidx]);
                acc[mcc] = __builtin_amdgcn_mfma_f32_16x16x32_bf16(aF, wf[ks], acc[mcc], 0, 0, 0);
            }
        }
    }

    // epilogue: out = x + acc*inv + bias ; rows cc contiguous in memory -> float4
    const size_t base = (size_t)(b * 256 + ch) * 3200 + tt * 400;
#pragma unroll
    for (int mcc = 0; mcc < 25; ++mcc) {
        const int cc0 = (mcc << 4) + (lg << 2);
        f32x4 r = *(const f32x4*)(x + base + cc0);
        f32x4 o4;
#pragma unroll
        for (int j = 0; j < 4; ++j) o4[j] = r[j] + acc[mcc][j] * inv + bias;
        *(f32x4*)(out + base + cc0) = o4;
    }
}

extern "C" void kernel_launch(void* const* d_in, const int* in_sizes, int n_in,
                              void* d_out, int out_size, void* d_ws, size_t ws_size,
                              hipStream_t stream) {
    const float* x     = (const float*)d_in[0];
    const float* A     = (const float*)d_in[1];
    const float* Wq    = (const float*)d_in[2];
    const float* Wk    = (const float*)d_in[3];
    const float* Wconv = (const float*)d_in[4];
    const float* alpha = (const float*)d_in[5];
    const float* gamma = (const float*)d_in[6];
    const float* beta  = (const float*)d_in[7];
    const float* rmean = (const float*)d_in[8];
    const float* rvar  = (const float*)d_in[9];
    float* out = (float*)d_out;

    float*  xm    = (float*)d_ws;
    __bf16* afull = (__bf16*)((char*)d_ws + 1638400);

    k_tmean<<<64 * 256, 256, 0, stream>>>(x, xm);
    k_adyn<<<64, 256, 0, stream>>>(xm, A, Wq, Wk, alpha, afull);
    k_main<<<64 * 4 * 8, 256, 0, stream>>>(x, Wconv, afull, gamma, beta, rmean, rvar, out);
}

// Round 2
// 235.844 us; speedup vs baseline: 1.3302x; 1.3302x over previous
//
#include <hip/hip_runtime.h>

typedef __bf16 bf16x8 __attribute__((ext_vector_type(8)));
typedef __bf16 bf16x4 __attribute__((ext_vector_type(4)));
typedef float  f32x4  __attribute__((ext_vector_type(4)));

// Shapes: B=64, C=256, T=128, V=25, K=3, G=4, Cg=64, dk=16
// ws: xm (64*256*25 f32 = 1,638,400 B) | afull (64*3*32*32 bf16 = 393,216 B)

// ---------------- Kernel 1: temporal mean xm[b,c,v] ----------------
// block = (b, c-pair). thread = (c_loc, t). 25 scalar loads (L1-local across the
// j-loop), 6-step 64-lane butterfly, cross-wave via tiny LDS.
__global__ __launch_bounds__(256)
void k_tmean(const float* __restrict__ x, float* __restrict__ xm)
{
    const int bid = blockIdx.x;            // b*128 + c2
    const int b = bid >> 7, c2 = bid & 127;
    const int tid = threadIdx.x;
    const int c_loc = tid >> 7, t = tid & 127;
    const int c = c2 * 2 + c_loc;
    const float* p = x + ((size_t)(b * 256 + c) * 128 + t) * 25;
    float v[25];
#pragma unroll
    for (int j = 0; j < 25; ++j) v[j] = p[j];
#pragma unroll
    for (int s = 1; s < 64; s <<= 1) {
#pragma unroll
        for (int j = 0; j < 25; ++j) v[j] += __shfl_xor(v[j], s);
    }
    __shared__ float part[4][25];
    if ((tid & 63) == 0) {
#pragma unroll
        for (int j = 0; j < 25; ++j) part[tid >> 6][j] = v[j];
    }
    __syncthreads();
    if (tid < 50) {
        const int cl = tid / 25, j = tid - cl * 25;
        xm[((size_t)(b * 256) + c2 * 2 + cl) * 25 + j] =
            (part[cl * 2][j] + part[cl * 2 + 1][j]) * (1.0f / 128.0f);
    }
}

// ---------------- Kernel 2: A_dyn + Afull tables (one block per b) ----------------
__global__ __launch_bounds__(256)
void k_adyn(const float* __restrict__ xm, const float* __restrict__ A,
            const float* __restrict__ Wq, const float* __restrict__ Wk,
            const float* __restrict__ alpha, __bf16* __restrict__ afull)
{
    const int b = blockIdx.x, tid = threadIdx.x;
    __shared__ float xm_s[256 * 25];
    __shared__ float q_s[64 * 25];
    __shared__ float k_s[64 * 25];
    __shared__ float sm_s[4][25][25];
    __shared__ float ad_s[25][25];
    __shared__ float rs_s[3][25];

    for (int i = tid; i < 256 * 25; i += 256) xm_s[i] = xm[(size_t)b * 6400 + i];
    for (int i = tid; i < 75; i += 256) {
        int k3 = i / 25, v = i - (i / 25) * 25;
        float s = 0.f;
        for (int w = 0; w < 25; ++w) s += A[(k3 * 25 + v) * 25 + w];
        rs_s[k3][v] = fmaxf(s, 1e-6f);
    }
    __syncthreads();

    for (int i = tid; i < 1600; i += 256) {
        int o = i / 25, v = i - o * 25;
        const float* wq = Wq + o * 256;
        const float* wk = Wk + o * 256;
        float aq = 0.f, ak = 0.f;
        for (int c = 0; c < 256; ++c) {
            float xv = xm_s[c * 25 + v];
            aq += wq[c] * xv;
            ak += wk[c] * xv;
        }
        q_s[i] = aq; k_s[i] = ak;
    }
    __syncthreads();

    if (tid < 100) {
        int g = tid / 25, v = tid - (tid / 25) * 25;
        float l[25];
#pragma unroll
        for (int w = 0; w < 25; ++w) {
            float s = 0.f;
#pragma unroll
            for (int d = 0; d < 16; ++d)
                s += q_s[(g * 16 + d) * 25 + v] * k_s[(g * 16 + d) * 25 + w];
            l[w] = s * 0.25f;
        }
        float mx = l[0];
#pragma unroll
        for (int w = 1; w < 25; ++w) mx = fmaxf(mx, l[w]);
        float den = 0.f;
#pragma unroll
        for (int w = 0; w < 25; ++w) { l[w] = expf(l[w] - mx); den += l[w]; }
        float rden = 1.f / den;
#pragma unroll
        for (int w = 0; w < 25; ++w) sm_s[g][v][w] = l[w] * rden;
    }
    __syncthreads();
    for (int i = tid; i < 625; i += 256) {
        int v = i / 25, w = i - (i / 25) * 25;
        ad_s[v][w] = 0.25f * (sm_s[0][v][w] + sm_s[1][v][w] + sm_s[2][v][w] + sm_s[3][v][w]);
    }
    __syncthreads();

    const float al = tanhf(alpha[0]);
    for (int i = tid; i < 3 * 32 * 32; i += 256) {
        int k3 = i >> 10, rem = i & 1023, v = rem >> 5, w = rem & 31;
        float val = 0.f;
        if (v < 25 && w < 25)
            val = A[(k3 * 25 + v) * 25 + w] / rs_s[k3][v] + al * ad_s[v][w];
        afull[(size_t)b * 3072 + i] = (__bf16)val;
    }
}

// ---------------- Kernel 3: fused agg (MFMA) + grouped conv (MFMA) + BN + residual ----------------
// block = (b, g, tt of 4 t). LDS: xs bf16 swizzled [c][t][32] (16 KB) + xagg [112][64] (14.3 KB).
// xs granule swizzle: granule = ((c*4+t)<<2 | chunk) ^ (c&7).
// xagg col swizzle:   col' = col ^ ((cc&7)<<3).
__global__ __launch_bounds__(256, 4)
void k_main(const float* __restrict__ x, const float* __restrict__ Wconv,
            const __bf16* __restrict__ afull,
            const float* __restrict__ gamma, const float* __restrict__ beta,
            const float* __restrict__ rmean, const float* __restrict__ rvar,
            float* __restrict__ out)
{
    const int bid = blockIdx.x;
    const int tt = bid & 31;
    const int g  = (bid >> 5) & 3;
    const int b  = bid >> 7;
    const int tid = threadIdx.x;
    const int wave = tid >> 6;
    const int lane = tid & 63;
    const int l15 = lane & 15;
    const int lg  = lane >> 4;

    __shared__ __bf16 xs[64 * 4 * 32];     // 16 KB
    __shared__ __bf16 xagg[112 * 64];      // 14.3 KB

    // ---- stage x slice -> xs (bf16, swizzled); thread = (c, t) row ----
    {
        const int c = tid >> 2, t = tid & 3;
        const float* p = x + ((size_t)(b * 256 + g * 64 + c) * 128 + tt * 4 + t) * 25;
        float r[25];
#pragma unroll
        for (int j = 0; j < 25; ++j) r[j] = p[j];
        const int rowg = (c * 4 + t) << 2;
        const int sw = c & 7;
#pragma unroll
        for (int ch = 0; ch < 4; ++ch) {
            bf16x8 h;
#pragma unroll
            for (int e = 0; e < 8; ++e) {
                const int v = ch * 8 + e;
                h[e] = (v < 25) ? (__bf16)r[v] : (__bf16)0.f;
            }
            *(bf16x8*)((char*)xs + (((rowg | ch) ^ sw) << 4)) = h;
        }
    }

    // ---- prefetch A-tables (all 3 k), issue Wconv k=0 loads ----
    bf16x8 bAf[3][2];
#pragma unroll
    for (int k3 = 0; k3 < 3; ++k3)
#pragma unroll
        for (int n = 0; n < 2; ++n)
            bAf[k3][n] = *(const bf16x8*)(afull + ((size_t)(b * 3 + k3) << 10) +
                                          (n * 16 + l15) * 32 + lg * 8);

    const int o_lane = (wave << 4) + l15;
    f32x4 wff[4];                          // in-flight f32 Wconv
    {
        const float* wp = Wconv + (size_t)((0 * 4 + g) * 64 + o_lane) * 64 + lg * 8;
        wff[0] = *(const f32x4*)wp;        wff[1] = *(const f32x4*)(wp + 4);
        wff[2] = *(const f32x4*)(wp + 32); wff[3] = *(const f32x4*)(wp + 36);
    }

    const int ch = g * 64 + o_lane;
    const float inv  = gamma[ch] / sqrtf(rvar[ch] + 1e-5f);
    const float bias = beta[ch] - rmean[ch] * inv;

    __syncthreads();

    // ---- fragments: lane (l15, lg) reads xs[c = m*16+l15][t=wave][chunk=lg] ----
    bf16x8 xfrag[4];
#pragma unroll
    for (int m = 0; m < 4; ++m) {
        const int c = m * 16 + l15;
        xfrag[m] = *(const bf16x8*)((char*)xs +
                      (((((c * 4 + wave) << 2) | lg) ^ (c & 7)) << 4));
    }

    f32x4 acc[7];
#pragma unroll
    for (int i = 0; i < 7; ++i) acc[i] = (f32x4){0.f, 0.f, 0.f, 0.f};
    const f32x4 zero4 = {0.f, 0.f, 0.f, 0.f};
    bf16x8 wfc[2];

#pragma unroll
    for (int k3 = 0; k3 < 3; ++k3) {
        // convert the in-flight Wconv f32 -> bf16 fragments
#pragma unroll
        for (int ks = 0; ks < 2; ++ks) {
            bf16x8 h;
#pragma unroll
            for (int e = 0; e < 4; ++e) {
                h[e]     = (__bf16)wff[ks * 2][e];
                h[e + 4] = (__bf16)wff[ks * 2 + 1][e];
            }
            wfc[ks] = h;
        }
        if (k3 < 2) {   // issue next k's Wconv loads (land during conv phase)
            const float* wp = Wconv + (size_t)(((k3 + 1) * 4 + g) * 64 + o_lane) * 64 + lg * 8;
            wff[0] = *(const f32x4*)wp;        wff[1] = *(const f32x4*)(wp + 4);
            wff[2] = *(const f32x4*)(wp + 32); wff[3] = *(const f32x4*)(wp + 36);
        }

        // aggregation: D[(t=wave, c-block m), v] -> xagg (swizzled bf16)
#pragma unroll
        for (int m = 0; m < 4; ++m) {
#pragma unroll
            for (int n = 0; n < 2; ++n) {
                f32x4 d = __builtin_amdgcn_mfma_f32_16x16x32_bf16(xfrag[m], bAf[k3][n],
                                                                  zero4, 0, 0, 0);
                const int v = n * 16 + l15;
                if (v < 25) {
                    const int cc  = wave * 25 + v;
                    const int col = (m * 16 + lg * 4) ^ ((cc & 7) << 3);
                    bf16x4 h;
                    h[0] = (__bf16)d[0]; h[1] = (__bf16)d[1];
                    h[2] = (__bf16)d[2]; h[3] = (__bf16)d[3];
                    *(bf16x4*)((char*)xagg + cc * 128 + col * 2) = h;
                }
            }
        }
        __syncthreads();

        // conv: acc[cc-tile, o] += xagg[cc, c] * W[o, c]
#pragma unroll
        for (int mcc = 0; mcc < 7; ++mcc) {
            const int cc = mcc * 16 + l15;
            const int sw2 = (cc & 7) << 3;
#pragma unroll
            for (int ks = 0; ks < 2; ++ks) {
                const int col = (ks * 32 + lg * 8) ^ sw2;
                bf16x8 aF = *(const bf16x8*)((char*)xagg + cc * 128 + col * 2);
                acc[mcc] = __builtin_amdgcn_mfma_f32_16x16x32_bf16(aF, wfc[ks],
                                                                   acc[mcc], 0, 0, 0);
            }
        }
        if (k3 < 2) __syncthreads();
    }

    // ---- epilogue: out = x + acc*inv + bias (residual from staged bf16 xs) ----
    const size_t obase = (size_t)(b * 256 + ch) * 3200 + tt * 100;
#pragma unroll
    for (int mcc = 0; mcc < 7; ++mcc) {
        const int cc0 = mcc * 16 + lg * 4;
        if (cc0 < 100) {
            f32x4 o4;
#pragma unroll
            for (int j = 0; j < 4; ++j) {
                const int cc = cc0 + j;
                const int t = cc / 25, v = cc - t * 25;
                const int gr = (((o_lane * 4 + t) << 2) | (v >> 3)) ^ (o_lane & 7);
                const float xr = (float)*(const __bf16*)((char*)xs + (gr << 4) + ((v & 7) << 1));
                o4[j] = xr + acc[mcc][j] * inv + bias;
            }
            *(f32x4*)(out + obase + cc0) = o4;
        }
    }
}

extern "C" void kernel_launch(void* const* d_in, const int* in_sizes, int n_in,
                              void* d_out, int out_size, void* d_ws, size_t ws_size,
                              hipStream_t stream) {
    const float* x     = (const float*)d_in[0];
    const float* A     = (const float*)d_in[1];
    const float* Wq    = (const float*)d_in[2];
    const float* Wk    = (const float*)d_in[3];
    const float* Wconv = (const float*)d_in[4];
    const float* alpha = (const float*)d_in[5];
    const float* gamma = (const float*)d_in[6];
    const float* beta  = (const float*)d_in[7];
    const float* rmean = (const float*)d_in[8];
    const float* rvar  = (const float*)d_in[9];
    float* out = (float*)d_out;

    float*  xm    = (float*)d_ws;
    __bf16* afull = (__bf16*)((char*)d_ws + 1638400);

    k_tmean<<<64 * 128, 256, 0, stream>>>(x, xm);
    k_adyn<<<64, 256, 0, stream>>>(xm, A, Wq, Wk, alpha, afull);
    k_main<<<64 * 4 * 32, 256, 0, stream>>>(x, Wconv, afull, gamma, beta, rmean, rvar, out);
}